// Round 3
// baseline (696.212 us; speedup 1.0000x reference)
//
#include <hip/hip_runtime.h>
#include <math.h>

typedef __bf16 bf16_t;
typedef __bf16 bf16x8 __attribute__((ext_vector_type(8)));
typedef float f32x4 __attribute__((ext_vector_type(4)));

// async global->LDS, 16B per lane; LDS dest is wave-uniform base + lane*16
#define LDS16(g, l) __builtin_amdgcn_global_load_lds( \
    (__attribute__((address_space(1))) void*)(g),     \
    (__attribute__((address_space(3))) void*)(l), 16, 0, 0)

// ---------------------------------------------------------------------------
// fp32 -> bf16 column-slice convert: out[r][0:take] = in[r][off:off+take]
// grid (ceil(take/1024), rows), block 256, 4 elems/thread
// ---------------------------------------------------------------------------
__global__ __launch_bounds__(256) void cvt_kernel(
    const float* __restrict__ in, bf16_t* __restrict__ out,
    int cols_in, int col_off, int cols_take)
{
    int row = blockIdx.y;
    int c = (blockIdx.x * 256 + threadIdx.x) * 4;
    if (c >= cols_take) return;
    float4 v = *(const float4*)(in + (size_t)row * cols_in + col_off + c);
    bf16_t* op = out + (size_t)row * cols_take + c;
    op[0] = (bf16_t)v.x; op[1] = (bf16_t)v.y;
    op[2] = (bf16_t)v.z; op[3] = (bf16_t)v.w;
}

// ---------------------------------------------------------------------------
// fp32 -> bf16 transpose: out[c][r] = in[r][c]   (for out_proj^T)
// ---------------------------------------------------------------------------
__global__ __launch_bounds__(256) void transpose_cvt_kernel(
    const float* __restrict__ in, bf16_t* __restrict__ out, int rows, int cols)
{
    __shared__ float tile[32][33];
    int c0 = blockIdx.x * 32, r0 = blockIdx.y * 32;
    int tx = threadIdx.x & 31, ty = threadIdx.x >> 5;  // 32 x 8
#pragma unroll
    for (int i = 0; i < 32; i += 8)
        tile[ty + i][tx] = in[(size_t)(r0 + ty + i) * cols + c0 + tx];
    __syncthreads();
#pragma unroll
    for (int i = 0; i < 32; i += 8)
        out[(size_t)(c0 + ty + i) * rows + r0 + tx] = (bf16_t)tile[tx][ty + i];
}

// ---------------------------------------------------------------------------
// bf16 -> bf16 batched transpose (V -> V^T)
// ---------------------------------------------------------------------------
__global__ __launch_bounds__(256) void transpose_bf16(
    const bf16_t* __restrict__ in, bf16_t* __restrict__ out,
    int rows, int cols, long long sIn, long long sOut)
{
    __shared__ bf16_t tile[32][33];
    int b = blockIdx.z;
    const bf16_t* ip = in + (long long)b * sIn;
    bf16_t* op = out + (long long)b * sOut;
    int c0 = blockIdx.x * 32, r0 = blockIdx.y * 32;
    int tx = threadIdx.x & 31, ty = threadIdx.x >> 5;
#pragma unroll
    for (int i = 0; i < 32; i += 8)
        tile[ty + i][tx] = ip[(size_t)(r0 + ty + i) * cols + c0 + tx];
    __syncthreads();
#pragma unroll
    for (int i = 0; i < 32; i += 8)
        op[(size_t)(c0 + ty + i) * rows + r0 + tx] = tile[tx][ty + i];
}

// ---------------------------------------------------------------------------
// RMSNorm: fp32 x in, bf16 h = x/rms(x) * w out. One block per row, D=1024.
// ---------------------------------------------------------------------------
__global__ __launch_bounds__(256) void rmsnorm_kernel(
    const float* __restrict__ x, const float* __restrict__ w,
    bf16_t* __restrict__ h)
{
    int row = blockIdx.x;
    int t = threadIdx.x;
    float4 xv = ((const float4*)(x + (size_t)row * 1024))[t];
    float ss = xv.x * xv.x + xv.y * xv.y + xv.z * xv.z + xv.w * xv.w;
#pragma unroll
    for (int o = 32; o > 0; o >>= 1) ss += __shfl_xor(ss, o, 64);
    __shared__ float red[4];
    if ((t & 63) == 0) red[t >> 6] = ss;
    __syncthreads();
    ss = red[0] + red[1] + red[2] + red[3];
    float rinv = rsqrtf(ss * (1.0f / 1024.0f) + 1e-5f);
    float4 wv = ((const float4*)w)[t];
    bf16_t* hp = h + (size_t)row * 1024 + t * 4;
    hp[0] = (bf16_t)(xv.x * rinv * wv.x);
    hp[1] = (bf16_t)(xv.y * rinv * wv.y);
    hp[2] = (bf16_t)(xv.z * rinv * wv.z);
    hp[3] = (bf16_t)(xv.w * rinv * wv.w);
}

// ---------------------------------------------------------------------------
// Causal softmax over bf16 scores, in place: row q keeps cols [0,q], rest -> 0
// ---------------------------------------------------------------------------
__global__ __launch_bounds__(256) void causal_softmax_kernel(bf16_t* __restrict__ SP)
{
    const int S = 2048;
    int q = blockIdx.x, b = blockIdx.y;
    bf16_t* row = SP + ((size_t)b * S + q) * S;
    int t = threadIdx.x;
    float v[8];
    float mx = -1e30f;
#pragma unroll
    for (int i = 0; i < 8; i++) {
        int j = i * 256 + t;
        v[i] = (j <= q) ? (float)row[j] : -1e30f;
        mx = fmaxf(mx, v[i]);
    }
#pragma unroll
    for (int o = 32; o > 0; o >>= 1) mx = fmaxf(mx, __shfl_xor(mx, o, 64));
    __shared__ float sm[4];
    if ((t & 63) == 0) sm[t >> 6] = mx;
    __syncthreads();
    mx = fmaxf(fmaxf(sm[0], sm[1]), fmaxf(sm[2], sm[3]));
    float e[8];
    float sum = 0.f;
#pragma unroll
    for (int i = 0; i < 8; i++) {
        e[i] = (v[i] > -1e29f) ? expf(v[i] - mx) : 0.f;
        sum += e[i];
    }
#pragma unroll
    for (int o = 32; o > 0; o >>= 1) sum += __shfl_xor(sum, o, 64);
    __shared__ float ssum[4];
    if ((t & 63) == 0) ssum[t >> 6] = sum;
    __syncthreads();
    sum = ssum[0] + ssum[1] + ssum[2] + ssum[3];
    float r = 1.0f / sum;
#pragma unroll
    for (int i = 0; i < 8; i++)
        row[i * 256 + t] = (bf16_t)(e[i] * r);
}

// ---------------------------------------------------------------------------
// MFMA GEMM: C[M,N] = A[M,K] * B[N,K]^T  (bf16 K-major operands), fp32 accum.
// 128x128 tile, BK=32, 256 threads = 4 waves (2x2), 64x64 per wave.
// EPI 0: bf16 C = v*scale
// EPI 1: bf16 C = gelu(v)
// EPI 2: fp32 C = v + R[row*N+col]  (R fp32; C may alias R exactly per-element,
//        so no __restrict__ on C/R and the load precedes the store)
// CSKIP: skip blocks strictly above diagonal (causal scores)
// CKLOOP: clamp K loop at (bm+1)*128 (causal attn*V; masked probs are 0)
// ---------------------------------------------------------------------------
template <int EPI, bool CSKIP, bool CKLOOP>
__global__ __launch_bounds__(256) void gemm_bt(
    const bf16_t* __restrict__ A, const bf16_t* __restrict__ B,
    void* Cv, const float* R,
    int N, int K, long long sA, long long sB, long long sC, float scale)
{
    int bn = blockIdx.x, bm = blockIdx.y, bz = blockIdx.z;
    if (CSKIP && bn > bm) return;
    __shared__ __align__(16) bf16_t At[128 * 32];
    __shared__ __align__(16) bf16_t Bt[128 * 32];
    int t = threadIdx.x;
    int w = t >> 6, l = t & 63;
    int wm = w >> 1, wn = w & 1;
    int lane_m = l & 15, quad = l >> 4;

    const bf16_t* Ag = A + (long long)bz * sA + (size_t)(bm * 128) * K;
    const bf16_t* Bg = B + (long long)bz * sB + (size_t)(bn * 128) * K;

    int Keff = K;
    if (CKLOOP) {
        int kk = (bm + 1) * 128;
        if (kk < K) Keff = kk;
    }

    f32x4 acc[4][4] = {};

    // staging: 16B chunk c covers tile row c>>2, cols ((c&3)*8 .. +8)
    int chunk0 = w * 64 + l;
    int chunk1 = (4 + w) * 64 + l;
    int r0 = chunk0 >> 2, c0 = (chunk0 & 3) * 8;
    int r1 = chunk1 >> 2, c1 = (chunk1 & 3) * 8;

    for (int kt = 0; kt < Keff; kt += 32) {
        __syncthreads();
        LDS16(Ag + (size_t)r0 * K + kt + c0, At + (size_t)w * 512);
        LDS16(Ag + (size_t)r1 * K + kt + c1, At + (size_t)(4 + w) * 512);
        LDS16(Bg + (size_t)r0 * K + kt + c0, Bt + (size_t)w * 512);
        LDS16(Bg + (size_t)r1 * K + kt + c1, Bt + (size_t)(4 + w) * 512);
        __syncthreads();

        bf16x8 af[4], bfr[4];
#pragma unroll
        for (int mi = 0; mi < 4; mi++)
            af[mi] = *(const bf16x8*)(At + (wm * 64 + mi * 16 + lane_m) * 32 + quad * 8);
#pragma unroll
        for (int ni = 0; ni < 4; ni++)
            bfr[ni] = *(const bf16x8*)(Bt + (wn * 64 + ni * 16 + lane_m) * 32 + quad * 8);
#pragma unroll
        for (int mi = 0; mi < 4; mi++)
#pragma unroll
            for (int ni = 0; ni < 4; ni++)
                acc[mi][ni] = __builtin_amdgcn_mfma_f32_16x16x32_bf16(
                    af[mi], bfr[ni], acc[mi][ni], 0, 0, 0);
    }

    long long cbase = (long long)bz * sC;
#pragma unroll
    for (int mi = 0; mi < 4; mi++) {
#pragma unroll
        for (int r = 0; r < 4; r++) {
            int row = bm * 128 + wm * 64 + mi * 16 + quad * 4 + r;
#pragma unroll
            for (int ni = 0; ni < 4; ni++) {
                int col = bn * 128 + wn * 64 + ni * 16 + lane_m;
                float v = acc[mi][ni][r];
                size_t idx = (size_t)(cbase + (long long)row * N + col);
                if (EPI == 0) {
                    ((bf16_t*)Cv)[idx] = (bf16_t)(v * scale);
                } else if (EPI == 1) {
                    float g = 0.5f * v * (1.0f + erff(v * 0.70710678118654752f));
                    ((bf16_t*)Cv)[idx] = (bf16_t)g;
                } else {
                    float rv = R[(size_t)row * N + col];
                    ((float*)Cv)[idx] = v + rv;
                }
            }
        }
    }
}

// ---------------------------------------------------------------------------
// Launch.  fp32 I/O; bf16 internals. Workspace peak 88 MiB:
//   [0,2)qpb [2,4)kpb [4,6)vpb [6,8)opT [8,16)f1b [16,20)f2h1 [20,24)f2h2
//   [24,40) h1, later h2
//   [40,56) Q,  later VT,  later G(lo)
//   [56,72) K,  later AV,  later G(hi)
//   [72,88) V
//   SP (bf16, 32 MiB) lives in d_out (fp32 out = 32 MiB, free until out_proj)
// ---------------------------------------------------------------------------
extern "C" void kernel_launch(void* const* d_in, const int* in_sizes, int n_in,
                              void* d_out, int out_size, void* d_ws, size_t ws_size,
                              hipStream_t stream)
{
    (void)in_sizes; (void)n_in; (void)out_size; (void)ws_size;
    const float* x    = (const float*)d_in[0];
    const float* ln1  = (const float*)d_in[1];
    const float* ln2  = (const float*)d_in[2];
    const float* ffn1 = (const float*)d_in[3];
    const float* ffn2 = (const float*)d_in[4];
    const float* kp   = (const float*)d_in[5];
    const float* qp   = (const float*)d_in[6];
    const float* vp   = (const float*)d_in[7];
    const float* op   = (const float*)d_in[8];
    float* out = (float*)d_out;

    const size_t MiB = 1048576;
    char* ws = (char*)d_ws;
    bf16_t* qpb  = (bf16_t*)(ws + 0 * MiB);
    bf16_t* kpb  = (bf16_t*)(ws + 2 * MiB);
    bf16_t* vpb  = (bf16_t*)(ws + 4 * MiB);
    bf16_t* opT  = (bf16_t*)(ws + 6 * MiB);
    bf16_t* f1b  = (bf16_t*)(ws + 8 * MiB);
    bf16_t* f2h1 = (bf16_t*)(ws + 16 * MiB);
    bf16_t* f2h2 = (bf16_t*)(ws + 20 * MiB);
    bf16_t* h1   = (bf16_t*)(ws + 24 * MiB);
    bf16_t* h2   = (bf16_t*)(ws + 24 * MiB);  // h1 dead after QKV
    bf16_t* Qb   = (bf16_t*)(ws + 40 * MiB);
    bf16_t* Kb   = (bf16_t*)(ws + 56 * MiB);
    bf16_t* Vb   = (bf16_t*)(ws + 72 * MiB);
    bf16_t* VT   = (bf16_t*)(ws + 40 * MiB);  // Q dead after scores
    bf16_t* AV   = (bf16_t*)(ws + 56 * MiB);  // K dead after scores
    bf16_t* G    = (bf16_t*)(ws + 40 * MiB);  // VT/AV dead after out_proj
    bf16_t* SP   = (bf16_t*)d_out;            // scores staged in d_out

    dim3 blk(256);

    // 0) weight converts fp32 -> bf16 (K-major as needed)
    cvt_kernel<<<dim3(1, 1024), blk, 0, stream>>>(qp, qpb, 1024, 0, 1024);
    cvt_kernel<<<dim3(1, 1024), blk, 0, stream>>>(kp, kpb, 1024, 0, 1024);
    cvt_kernel<<<dim3(1, 1024), blk, 0, stream>>>(vp, vpb, 1024, 0, 1024);
    transpose_cvt_kernel<<<dim3(32, 32), blk, 0, stream>>>(op, opT, 1024, 1024);
    cvt_kernel<<<dim3(1, 4096), blk, 0, stream>>>(ffn1, f1b, 1024, 0, 1024);
    cvt_kernel<<<dim3(2, 1024), blk, 0, stream>>>(ffn2, f2h1, 4096, 0, 2048);
    cvt_kernel<<<dim3(2, 1024), blk, 0, stream>>>(ffn2, f2h2, 4096, 2048, 2048);

    // 1) h1 = rmsnorm(x) * ln1   (fp32 in, bf16 out)
    rmsnorm_kernel<<<dim3(8192), blk, 0, stream>>>(x, ln1, h1);

    // 2) Q/K/V projections: [8192,1024] x [1024,1024]^T -> bf16
    gemm_bt<0, false, false><<<dim3(8, 64, 1), blk, 0, stream>>>(
        h1, qpb, Qb, nullptr, 1024, 1024, 0, 0, 0, 1.0f);
    gemm_bt<0, false, false><<<dim3(8, 64, 1), blk, 0, stream>>>(
        h1, kpb, Kb, nullptr, 1024, 1024, 0, 0, 0, 1.0f);
    gemm_bt<0, false, false><<<dim3(8, 64, 1), blk, 0, stream>>>(
        h1, vpb, Vb, nullptr, 1024, 1024, 0, 0, 0, 1.0f);

    // 3) scores = Q K^T / 32, lower-triangular blocks only -> SP (in d_out)
    gemm_bt<0, true, false><<<dim3(16, 16, 4), blk, 0, stream>>>(
        Qb, Kb, SP, nullptr, 2048, 1024,
        (long long)2048 * 1024, (long long)2048 * 1024, (long long)2048 * 2048,
        1.0f / 32.0f);

    // 4) V -> V^T per batch (into Q slot)
    transpose_bf16<<<dim3(32, 64, 4), blk, 0, stream>>>(
        Vb, VT, 2048, 1024, (long long)2048 * 1024, (long long)1024 * 2048);

    // 5) causal softmax in place (zeros above diagonal everywhere)
    causal_softmax_kernel<<<dim3(2048, 4), blk, 0, stream>>>(SP);

    // 6) AV = P @ V  (B = V^T, causal K clamp; into K slot)
    gemm_bt<0, false, true><<<dim3(8, 16, 4), blk, 0, stream>>>(
        SP, VT, AV, nullptr, 1024, 2048,
        (long long)2048 * 2048, (long long)1024 * 2048, (long long)2048 * 1024,
        1.0f);

    // 7) out = x + AV @ out_proj   (fp32 into d_out; SP dead)
    gemm_bt<2, false, false><<<dim3(8, 64, 1), blk, 0, stream>>>(
        AV, opT, out, x, 1024, 1024, 0, 0, 0, 1.0f);

    // 8) h2 = rmsnorm(x) * ln2  (h1 slot)
    rmsnorm_kernel<<<dim3(8192), blk, 0, stream>>>(x, ln2, h2);

    // 9a) G = gelu(h2 @ ffn1[0:2048]^T)   [8192,2048] bf16
    gemm_bt<1, false, false><<<dim3(16, 64, 1), blk, 0, stream>>>(
        h2, f1b, G, nullptr, 2048, 1024, 0, 0, 0, 1.0f);
    // 9b) out += G @ ffn2[:,0:2048]^T   (aliased fp32 read-add-write)
    gemm_bt<2, false, false><<<dim3(8, 64, 1), blk, 0, stream>>>(
        G, f2h1, out, out, 1024, 2048, 0, 0, 0, 1.0f);
    // 10a) G = gelu(h2 @ ffn1[2048:4096]^T)
    gemm_bt<1, false, false><<<dim3(16, 64, 1), blk, 0, stream>>>(
        h2, f1b + (size_t)2048 * 1024, G, nullptr, 2048, 1024, 0, 0, 0, 1.0f);
    // 10b) out += G @ ffn2[:,2048:4096]^T
    gemm_bt<2, false, false><<<dim3(8, 64, 1), blk, 0, stream>>>(
        G, f2h2, out, out, 1024, 2048, 0, 0, 0, 1.0f);
}

// Round 4
// 636.549 us; speedup vs baseline: 1.0937x; 1.0937x over previous
//
#include <hip/hip_runtime.h>
#include <math.h>

typedef __bf16 bf16_t;
typedef __bf16 bf16x8 __attribute__((ext_vector_type(8)));
typedef float f32x4 __attribute__((ext_vector_type(4)));

// async global->LDS, 16B per lane; LDS dest is wave-uniform base + lane*16
#define LDS16(g, l) __builtin_amdgcn_global_load_lds( \
    (__attribute__((address_space(1))) void*)(g),     \
    (__attribute__((address_space(3))) void*)(l), 16, 0, 0)

// ---------------------------------------------------------------------------
// One-shot fp32 -> bf16 weight convert (flat copies):
//   [0,1M)   qp -> qkvb rows 0-1023
//   [1M,2M)  kp -> qkvb rows 1024-2047
//   [2M,3M)  vp -> qkvb rows 2048-3071
//   [3M,7M)  ffn1 -> f1b
//   [7M,11M) ffn2 -> f2b
// ---------------------------------------------------------------------------
__global__ __launch_bounds__(256) void cvt_all_kernel(
    const float* __restrict__ qp, const float* __restrict__ kp,
    const float* __restrict__ vp, const float* __restrict__ f1,
    const float* __restrict__ f2, bf16_t* __restrict__ qkvb,
    bf16_t* __restrict__ f1b, bf16_t* __restrict__ f2b)
{
    size_t i = ((size_t)blockIdx.x * 256 + threadIdx.x) * 4;
    const float* src;
    bf16_t* dst;
    if (i < 3145728) {
        if (i < 1048576)      { src = qp + i;            dst = qkvb + i; }
        else if (i < 2097152) { src = kp + (i - 1048576); dst = qkvb + i; }
        else                  { src = vp + (i - 2097152); dst = qkvb + i; }
    } else if (i < 7340032) { src = f1 + (i - 3145728); dst = f1b + (i - 3145728); }
    else                    { src = f2 + (i - 7340032); dst = f2b + (i - 7340032); }
    float4 v = *(const float4*)src;
    dst[0] = (bf16_t)v.x; dst[1] = (bf16_t)v.y;
    dst[2] = (bf16_t)v.z; dst[3] = (bf16_t)v.w;
}

// ---------------------------------------------------------------------------
// fp32 -> bf16 transpose (out_proj^T), 1024x1024
// ---------------------------------------------------------------------------
__global__ __launch_bounds__(256) void transpose_cvt_kernel(
    const float* __restrict__ in, bf16_t* __restrict__ out, int rows, int cols)
{
    __shared__ float tile[32][33];
    int c0 = blockIdx.x * 32, r0 = blockIdx.y * 32;
    int tx = threadIdx.x & 31, ty = threadIdx.x >> 5;  // 32 x 8
#pragma unroll
    for (int i = 0; i < 32; i += 8)
        tile[ty + i][tx] = in[(size_t)(r0 + ty + i) * cols + c0 + tx];
    __syncthreads();
#pragma unroll
    for (int i = 0; i < 32; i += 8)
        out[(size_t)(c0 + ty + i) * rows + r0 + tx] = (bf16_t)tile[tx][ty + i];
}

// ---------------------------------------------------------------------------
// bf16 batched transpose with input row stride: out[c][r] = in[r*ldin + c]
// ---------------------------------------------------------------------------
__global__ __launch_bounds__(256) void transpose_bf16(
    const bf16_t* __restrict__ in, bf16_t* __restrict__ out,
    int rows, int ldin, long long sIn, long long sOut)
{
    __shared__ bf16_t tile[32][33];
    int b = blockIdx.z;
    const bf16_t* ip = in + (long long)b * sIn;
    bf16_t* op = out + (long long)b * sOut;
    int c0 = blockIdx.x * 32, r0 = blockIdx.y * 32;
    int tx = threadIdx.x & 31, ty = threadIdx.x >> 5;
#pragma unroll
    for (int i = 0; i < 32; i += 8)
        tile[ty + i][tx] = ip[(size_t)(r0 + ty + i) * ldin + c0 + tx];
    __syncthreads();
#pragma unroll
    for (int i = 0; i < 32; i += 8)
        op[(size_t)(c0 + ty + i) * rows + r0 + tx] = tile[tx][ty + i];
}

// ---------------------------------------------------------------------------
// RMSNorm: fp32 x in, bf16 h = x/rms(x) * w out. One block per row, D=1024.
// ---------------------------------------------------------------------------
__global__ __launch_bounds__(256) void rmsnorm_kernel(
    const float* __restrict__ x, const float* __restrict__ w,
    bf16_t* __restrict__ h)
{
    int row = blockIdx.x;
    int t = threadIdx.x;
    float4 xv = ((const float4*)(x + (size_t)row * 1024))[t];
    float ss = xv.x * xv.x + xv.y * xv.y + xv.z * xv.z + xv.w * xv.w;
#pragma unroll
    for (int o = 32; o > 0; o >>= 1) ss += __shfl_xor(ss, o, 64);
    __shared__ float red[4];
    if ((t & 63) == 0) red[t >> 6] = ss;
    __syncthreads();
    ss = red[0] + red[1] + red[2] + red[3];
    float rinv = rsqrtf(ss * (1.0f / 1024.0f) + 1e-5f);
    float4 wv = ((const float4*)w)[t];
    bf16_t* hp = h + (size_t)row * 1024 + t * 4;
    hp[0] = (bf16_t)(xv.x * rinv * wv.x);
    hp[1] = (bf16_t)(xv.y * rinv * wv.y);
    hp[2] = (bf16_t)(xv.z * rinv * wv.z);
    hp[3] = (bf16_t)(xv.w * rinv * wv.w);
}

// ---------------------------------------------------------------------------
// Causal softmax over bf16 scores, in place: row q keeps cols [0,q], rest -> 0
// ---------------------------------------------------------------------------
__global__ __launch_bounds__(256) void causal_softmax_kernel(bf16_t* __restrict__ SP)
{
    const int S = 2048;
    int q = blockIdx.x, b = blockIdx.y;
    bf16_t* row = SP + ((size_t)b * S + q) * S;
    int t = threadIdx.x;
    float v[8];
    float mx = -1e30f;
#pragma unroll
    for (int i = 0; i < 8; i++) {
        int j = i * 256 + t;
        v[i] = (j <= q) ? (float)row[j] : -1e30f;
        mx = fmaxf(mx, v[i]);
    }
#pragma unroll
    for (int o = 32; o > 0; o >>= 1) mx = fmaxf(mx, __shfl_xor(mx, o, 64));
    __shared__ float sm[4];
    if ((t & 63) == 0) sm[t >> 6] = mx;
    __syncthreads();
    mx = fmaxf(fmaxf(sm[0], sm[1]), fmaxf(sm[2], sm[3]));
    float e[8];
    float sum = 0.f;
#pragma unroll
    for (int i = 0; i < 8; i++) {
        e[i] = (v[i] > -1e29f) ? expf(v[i] - mx) : 0.f;
        sum += e[i];
    }
#pragma unroll
    for (int o = 32; o > 0; o >>= 1) sum += __shfl_xor(sum, o, 64);
    __shared__ float ssum[4];
    if ((t & 63) == 0) ssum[t >> 6] = sum;
    __syncthreads();
    sum = ssum[0] + ssum[1] + ssum[2] + ssum[3];
    float r = 1.0f / sum;
#pragma unroll
    for (int i = 0; i < 8; i++)
        row[i * 256 + t] = (bf16_t)(e[i] * r);
}

// ---------------------------------------------------------------------------
// MFMA GEMM: C[M,N] = A * B^T, A row-major [M][lda-strided, K used],
// B row-major [N][ldb-strided, K used], fp32 accum. 128x128 tile, BK=32,
// 4 waves (2x2), 64x64/wave, 16x16x32 bf16 MFMA.
//
// LDS tile [128 rows][4 slots x 8 bf16], slot XOR-swizzled: global k-group g
// for row r lives in slot s = g ^ ((r>>1)&3). ds_read_b128 then hits each
// bank pair exactly twice per 16-lane phase (2-way = free, vs 8-way before).
//
// Grid: 1D x (+z batch). XCD-aware decode: xcd = id&7 owns a contiguous
// chunk of bm values so all bn-blocks sharing an A-tile land on one XCD's L2.
//
// EPI 0: bf16 C = v*scale | EPI 1: bf16 C = gelu(v) | EPI 2: fp32 C = v + R
// (EPI2: C may alias R per-element -> no restrict, load precedes store)
// CSKIP: skip tiles strictly above diagonal. CKLOOP: Keff = min(K,(bm+1)*128).
// ---------------------------------------------------------------------------
template <int EPI, bool CSKIP, bool CKLOOP>
__global__ __launch_bounds__(256) void gemm_bt(
    const bf16_t* __restrict__ A, int lda, const bf16_t* __restrict__ B, int ldb,
    void* Cv, int ldc, const float* R,
    int K, int Mt, long long sA, long long sB, long long sC, float scale)
{
    int id = blockIdx.x, bz = blockIdx.z;
    int xcd = id & 7, p = id >> 3;
    int chunk = Mt >> 3;
    int bm = xcd * chunk + (p % chunk);
    int bn = p / chunk;
    if (CSKIP && bn > bm) return;

    __shared__ __align__(16) bf16_t At[128 * 32];
    __shared__ __align__(16) bf16_t Bt[128 * 32];
    int t = threadIdx.x;
    int w = t >> 6, l = t & 63;
    int wm = w >> 1, wn = w & 1;
    int lane_m = l & 15, quad = l >> 4;

    const bf16_t* Ag = A + (long long)bz * sA + (size_t)(bm * 128) * lda;
    const bf16_t* Bg = B + (long long)bz * sB + (size_t)(bn * 128) * ldb;

    int Keff = K;
    if (CKLOOP) {
        int kk = (bm + 1) * 128;
        if (kk < K) Keff = kk;
    }

    f32x4 acc[4][4] = {};

    // staging: wave w stages chunks [w*64, w*64+64) and +256. chunk c ->
    // LDS row r=c>>2 slot s=c&3; source k-group g = s ^ ((r>>1)&3).
    int r0 = w * 16 + (l >> 2);          // chunk0 = w*64 + l
    int g0 = ((l & 3) ^ ((l >> 3) & 3)) * 8;
    int r1 = r0 + 64;                     // chunk1 = chunk0 + 256, same g
    const bf16_t* a0 = Ag + (size_t)r0 * lda + g0;
    const bf16_t* a1 = Ag + (size_t)r1 * lda + g0;
    const bf16_t* b0 = Bg + (size_t)r0 * ldb + g0;
    const bf16_t* b1 = Bg + (size_t)r1 * ldb + g0;

    // ds_read slot swizzle: row = wm*64 + mi*16 + lane_m; (row>>1)&3 depends
    // only on lane_m (wm*64, mi*16 are 0 mod 8 in row>>1 space)
    int sa = (quad ^ ((lane_m >> 1) & 3)) * 8;

    for (int kt = 0; kt < Keff; kt += 32) {
        __syncthreads();
        LDS16(a0 + kt, At + (size_t)w * 512);
        LDS16(a1 + kt, At + (size_t)(4 + w) * 512);
        LDS16(b0 + kt, Bt + (size_t)w * 512);
        LDS16(b1 + kt, Bt + (size_t)(4 + w) * 512);
        __syncthreads();

        bf16x8 af[4], bfr[4];
#pragma unroll
        for (int mi = 0; mi < 4; mi++)
            af[mi] = *(const bf16x8*)(At + (wm * 64 + mi * 16 + lane_m) * 32 + sa);
#pragma unroll
        for (int ni = 0; ni < 4; ni++)
            bfr[ni] = *(const bf16x8*)(Bt + (wn * 64 + ni * 16 + lane_m) * 32 + sa);
#pragma unroll
        for (int mi = 0; mi < 4; mi++)
#pragma unroll
            for (int ni = 0; ni < 4; ni++)
                acc[mi][ni] = __builtin_amdgcn_mfma_f32_16x16x32_bf16(
                    af[mi], bfr[ni], acc[mi][ni], 0, 0, 0);
    }

    long long cbase = (long long)bz * sC;
#pragma unroll
    for (int mi = 0; mi < 4; mi++) {
#pragma unroll
        for (int r = 0; r < 4; r++) {
            int row = bm * 128 + wm * 64 + mi * 16 + quad * 4 + r;
#pragma unroll
            for (int ni = 0; ni < 4; ni++) {
                int col = bn * 128 + wn * 64 + ni * 16 + lane_m;
                float v = acc[mi][ni][r];
                size_t idx = (size_t)(cbase + (long long)row * ldc + col);
                if (EPI == 0) {
                    ((bf16_t*)Cv)[idx] = (bf16_t)(v * scale);
                } else if (EPI == 1) {
                    float g = 0.5f * v * (1.0f + erff(v * 0.70710678118654752f));
                    ((bf16_t*)Cv)[idx] = (bf16_t)g;
                } else {
                    float rv = R[(size_t)row * ldc + col];
                    ((float*)Cv)[idx] = v + rv;
                }
            }
        }
    }
}

// ---------------------------------------------------------------------------
// Launch. fp32 I/O, bf16 internals. Workspace peak 88 MiB:
//   [0,6)   qkvb  (weights, [3072][1024])
//   [6,8)   opT
//   [8,16)  f1b   [4096][1024]
//   [16,24) f2b   [1024][4096]
//   [24,40) h1 -> VT -> h2      (disjoint lifetimes)
//   [40,88) QKVb [8192][3072];  then AV [40,56);  then G [40,72)
//   SP (bf16 32 MiB) lives in d_out (fp32 out unused until out_proj)
// ---------------------------------------------------------------------------
extern "C" void kernel_launch(void* const* d_in, const int* in_sizes, int n_in,
                              void* d_out, int out_size, void* d_ws, size_t ws_size,
                              hipStream_t stream)
{
    (void)in_sizes; (void)n_in; (void)out_size; (void)ws_size;
    const float* x    = (const float*)d_in[0];
    const float* ln1  = (const float*)d_in[1];
    const float* ln2  = (const float*)d_in[2];
    const float* ffn1 = (const float*)d_in[3];
    const float* ffn2 = (const float*)d_in[4];
    const float* kp   = (const float*)d_in[5];
    const float* qp   = (const float*)d_in[6];
    const float* vp   = (const float*)d_in[7];
    const float* op   = (const float*)d_in[8];
    float* out = (float*)d_out;

    const size_t MiB = 1048576;
    char* ws = (char*)d_ws;
    bf16_t* qkvb = (bf16_t*)(ws + 0 * MiB);
    bf16_t* opT  = (bf16_t*)(ws + 6 * MiB);
    bf16_t* f1b  = (bf16_t*)(ws + 8 * MiB);
    bf16_t* f2b  = (bf16_t*)(ws + 16 * MiB);
    bf16_t* h1   = (bf16_t*)(ws + 24 * MiB);
    bf16_t* VT   = (bf16_t*)(ws + 24 * MiB);  // h1 dead after QKV gemm
    bf16_t* h2   = (bf16_t*)(ws + 24 * MiB);  // VT dead after AV gemm
    bf16_t* QKVb = (bf16_t*)(ws + 40 * MiB);  // [8192][3072]
    bf16_t* AV   = (bf16_t*)(ws + 40 * MiB);  // QKVb dead after V^T
    bf16_t* G    = (bf16_t*)(ws + 40 * MiB);  // AV dead after out_proj
    bf16_t* SP   = (bf16_t*)d_out;

    dim3 blk(256);

    // 0) weight converts (1 flat kernel + out_proj^T)
    cvt_all_kernel<<<dim3(11264), blk, 0, stream>>>(
        qp, kp, vp, ffn1, ffn2, qkvb, f1b, f2b);
    transpose_cvt_kernel<<<dim3(32, 32), blk, 0, stream>>>(op, opT, 1024, 1024);

    // 1) h1 = rmsnorm(x) * ln1
    rmsnorm_kernel<<<dim3(8192), blk, 0, stream>>>(x, ln1, h1);

    // 2) fused QKV: [8192,1024] x [3072,1024]^T -> QKVb [8192][3072]
    gemm_bt<0, false, false><<<dim3(1536), blk, 0, stream>>>(
        h1, 1024, qkvb, 1024, QKVb, 3072, nullptr, 1024, 64, 0, 0, 0, 1.0f);

    // 3) scores = Q K^T / 32, lower-triangular tiles only -> SP (in d_out)
    gemm_bt<0, true, false><<<dim3(256, 1, 4), blk, 0, stream>>>(
        QKVb, 3072, QKVb + 1024, 3072, SP, 2048, nullptr, 1024, 16,
        (long long)2048 * 3072, (long long)2048 * 3072, (long long)2048 * 2048,
        1.0f / 32.0f);

    // 4) V -> V^T per batch (V = QKVb cols [2048,3072); VT into h1 slot)
    transpose_bf16<<<dim3(32, 64, 4), blk, 0, stream>>>(
        QKVb + 2048, VT, 2048, 3072, (long long)2048 * 3072, (long long)1024 * 2048);

    // 5) causal softmax in place
    causal_softmax_kernel<<<dim3(2048, 4), blk, 0, stream>>>(SP);

    // 6) AV = P @ V (B = V^T [1024][2048], causal K clamp; QKVb slot reused)
    gemm_bt<0, false, true><<<dim3(128, 1, 4), blk, 0, stream>>>(
        SP, 2048, VT, 2048, AV, 1024, nullptr, 2048, 16,
        (long long)2048 * 2048, (long long)1024 * 2048, (long long)2048 * 1024,
        1.0f);

    // 7) out = x + AV @ out_proj^T  (fp32 into d_out; SP dead)
    gemm_bt<2, false, false><<<dim3(512), blk, 0, stream>>>(
        AV, 1024, opT, 1024, out, 1024, x, 1024, 64, 0, 0, 0, 1.0f);

    // 8) h2 = rmsnorm(x) * ln2  (VT slot)
    rmsnorm_kernel<<<dim3(8192), blk, 0, stream>>>(x, ln2, h2);

    // 9/10) FFN in two N-halves of ffn1 (G is 32 MiB), K-halves of ffn2
    for (int half = 0; half < 2; half++) {
        gemm_bt<1, false, false><<<dim3(1024), blk, 0, stream>>>(
            h2, 1024, f1b + (size_t)half * 2048 * 1024, 1024, G, 2048, nullptr,
            1024, 64, 0, 0, 0, 1.0f);
        gemm_bt<2, false, false><<<dim3(512), blk, 0, stream>>>(
            G, 2048, f2b + half * 2048, 4096, out, 1024, out,
            2048, 64, 0, 0, 0, 1.0f);
    }
}

// Round 5
// 543.958 us; speedup vs baseline: 1.2799x; 1.1702x over previous
//
#include <hip/hip_runtime.h>
#include <math.h>

typedef __bf16 bf16_t;
typedef __bf16 bf16x8 __attribute__((ext_vector_type(8)));
typedef float f32x4 __attribute__((ext_vector_type(4)));

// async global->LDS, 16B per lane; LDS dest is wave-uniform base + lane*16
#define LDS16(g, l) __builtin_amdgcn_global_load_lds( \
    (__attribute__((address_space(1))) void*)(g),     \
    (__attribute__((address_space(3))) void*)(l), 16, 0, 0)

// ---------------------------------------------------------------------------
// Prep kernel: blocks [0,11264) fp32->bf16 flat weight cvt;
// [11264,12288) out_proj^T (32x32 tiles); [12288,20480) rmsnorm(x)*ln1 -> h1
// ---------------------------------------------------------------------------
__global__ __launch_bounds__(256) void prep_kernel(
    const float* __restrict__ qp, const float* __restrict__ kp,
    const float* __restrict__ vp, const float* __restrict__ f1,
    const float* __restrict__ f2, const float* __restrict__ op,
    const float* __restrict__ x, const float* __restrict__ ln1,
    bf16_t* __restrict__ qkvb, bf16_t* __restrict__ f1b,
    bf16_t* __restrict__ f2b, bf16_t* __restrict__ opT,
    bf16_t* __restrict__ h1)
{
    __shared__ float tile[32][33];
    __shared__ float red[4];
    int bid = blockIdx.x;
    int t = threadIdx.x;
    if (bid < 11264) {
        size_t i = ((size_t)bid * 256 + t) * 4;
        const float* src;
        bf16_t* dst;
        if (i < 3145728) {
            if (i < 1048576)      { src = qp + i;             dst = qkvb + i; }
            else if (i < 2097152) { src = kp + (i - 1048576); dst = qkvb + i; }
            else                  { src = vp + (i - 2097152); dst = qkvb + i; }
        } else if (i < 7340032) { src = f1 + (i - 3145728); dst = f1b + (i - 3145728); }
        else                    { src = f2 + (i - 7340032); dst = f2b + (i - 7340032); }
        float4 v = *(const float4*)src;
        dst[0] = (bf16_t)v.x; dst[1] = (bf16_t)v.y;
        dst[2] = (bf16_t)v.z; dst[3] = (bf16_t)v.w;
    } else if (bid < 12288) {
        int b2 = bid - 11264;
        int c0 = (b2 & 31) * 32, r0 = (b2 >> 5) * 32;
        int tx = t & 31, ty = t >> 5;  // 32 x 8
#pragma unroll
        for (int i = 0; i < 32; i += 8)
            tile[ty + i][tx] = op[(size_t)(r0 + ty + i) * 1024 + c0 + tx];
        __syncthreads();
#pragma unroll
        for (int i = 0; i < 32; i += 8)
            opT[(size_t)(c0 + ty + i) * 1024 + r0 + tx] = (bf16_t)tile[tx][ty + i];
    } else {
        int row = bid - 12288;
        float4 xv = ((const float4*)(x + (size_t)row * 1024))[t];
        float ss = xv.x * xv.x + xv.y * xv.y + xv.z * xv.z + xv.w * xv.w;
#pragma unroll
        for (int o = 32; o > 0; o >>= 1) ss += __shfl_xor(ss, o, 64);
        if ((t & 63) == 0) red[t >> 6] = ss;
        __syncthreads();
        ss = red[0] + red[1] + red[2] + red[3];
        float rinv = rsqrtf(ss * (1.0f / 1024.0f) + 1e-5f);
        float4 wv = ((const float4*)ln1)[t];
        bf16_t* hp = h1 + (size_t)row * 1024 + t * 4;
        hp[0] = (bf16_t)(xv.x * rinv * wv.x);
        hp[1] = (bf16_t)(xv.y * rinv * wv.y);
        hp[2] = (bf16_t)(xv.z * rinv * wv.z);
        hp[3] = (bf16_t)(xv.w * rinv * wv.w);
    }
}

// ---------------------------------------------------------------------------
// RMSNorm standalone (for h2): fp32 x in, bf16 h = x/rms(x)*w
// ---------------------------------------------------------------------------
__global__ __launch_bounds__(256) void rmsnorm_kernel(
    const float* __restrict__ x, const float* __restrict__ w,
    bf16_t* __restrict__ h)
{
    int row = blockIdx.x;
    int t = threadIdx.x;
    float4 xv = ((const float4*)(x + (size_t)row * 1024))[t];
    float ss = xv.x * xv.x + xv.y * xv.y + xv.z * xv.z + xv.w * xv.w;
#pragma unroll
    for (int o = 32; o > 0; o >>= 1) ss += __shfl_xor(ss, o, 64);
    __shared__ float red[4];
    if ((t & 63) == 0) red[t >> 6] = ss;
    __syncthreads();
    ss = red[0] + red[1] + red[2] + red[3];
    float rinv = rsqrtf(ss * (1.0f / 1024.0f) + 1e-5f);
    float4 wv = ((const float4*)w)[t];
    bf16_t* hp = h + (size_t)row * 1024 + t * 4;
    hp[0] = (bf16_t)(xv.x * rinv * wv.x);
    hp[1] = (bf16_t)(xv.y * rinv * wv.y);
    hp[2] = (bf16_t)(xv.z * rinv * wv.z);
    hp[3] = (bf16_t)(xv.w * rinv * wv.w);
}

// ---------------------------------------------------------------------------
// bf16 batched transpose with input row stride: out[c][r] = in[r*ldin + c]
// ---------------------------------------------------------------------------
__global__ __launch_bounds__(256) void transpose_bf16(
    const bf16_t* __restrict__ in, bf16_t* __restrict__ out,
    int rows, int ldin, long long sIn, long long sOut)
{
    __shared__ bf16_t tile[32][33];
    int b = blockIdx.z;
    const bf16_t* ip = in + (long long)b * sIn;
    bf16_t* op = out + (long long)b * sOut;
    int c0 = blockIdx.x * 32, r0 = blockIdx.y * 32;
    int tx = threadIdx.x & 31, ty = threadIdx.x >> 5;
#pragma unroll
    for (int i = 0; i < 32; i += 8)
        tile[ty + i][tx] = ip[(size_t)(r0 + ty + i) * ldin + c0 + tx];
    __syncthreads();
#pragma unroll
    for (int i = 0; i < 32; i += 8)
        op[(size_t)(c0 + ty + i) * rows + r0 + tx] = tile[tx][ty + i];
}

// ---------------------------------------------------------------------------
// Causal softmax, in place, vectorized. Row q: softmax over cols [0,q];
// writes zeros on (q, Jstore) where Jstore = next 128-boundary (all AV-gemm
// ever reads, due to its K-clamp). Cols >= Jstore left untouched.
// ---------------------------------------------------------------------------
__global__ __launch_bounds__(256) void causal_softmax_kernel(bf16_t* __restrict__ SP)
{
    const int S = 2048;
    int q = blockIdx.x, b = blockIdx.y;
    bf16_t* row = SP + ((size_t)b * S + q) * S;
    int t = threadIdx.x;
    int j0 = t * 8;
    int Jstore = ((q >> 7) + 1) << 7;

    float v[8];
    if (j0 + 7 <= q) {
        bf16x8 xv = *(const bf16x8*)(row + j0);
#pragma unroll
        for (int i = 0; i < 8; i++) v[i] = (float)xv[i];
    } else if (j0 <= q) {
#pragma unroll
        for (int i = 0; i < 8; i++)
            v[i] = (j0 + i <= q) ? (float)row[j0 + i] : -1e30f;
    } else {
#pragma unroll
        for (int i = 0; i < 8; i++) v[i] = -1e30f;
    }

    float mx = v[0];
#pragma unroll
    for (int i = 1; i < 8; i++) mx = fmaxf(mx, v[i]);
#pragma unroll
    for (int o = 32; o > 0; o >>= 1) mx = fmaxf(mx, __shfl_xor(mx, o, 64));
    __shared__ float sm[4], ssum[4];
    if ((t & 63) == 0) sm[t >> 6] = mx;
    __syncthreads();
    mx = fmaxf(fmaxf(sm[0], sm[1]), fmaxf(sm[2], sm[3]));

    float e[8];
    float sum = 0.f;
#pragma unroll
    for (int i = 0; i < 8; i++) {
        e[i] = (v[i] > -1e29f) ? expf(v[i] - mx) : 0.f;
        sum += e[i];
    }
#pragma unroll
    for (int o = 32; o > 0; o >>= 1) sum += __shfl_xor(sum, o, 64);
    if ((t & 63) == 0) ssum[t >> 6] = sum;
    __syncthreads();
    sum = ssum[0] + ssum[1] + ssum[2] + ssum[3];
    float r = 1.0f / sum;

    if (j0 < Jstore) {
        bf16x8 ov;
#pragma unroll
        for (int i = 0; i < 8; i++) ov[i] = (bf16_t)(e[i] * r);
        *(bf16x8*)(row + j0) = ov;
    }
}

// ---------------------------------------------------------------------------
// MFMA GEMM: C[M,N] = A * B^T, A [M][lda] row-major (K used), B [N][ldb]
// row-major (K used), fp32 accum. 128x128 tile, BK=64, 4 waves (2x2),
// 64x64/wave, 16x16x32 bf16 MFMA, 2 K-halves per LDS tile.
//
// LDS tile [128 rows][8 slots x 8 bf16] (16 KB each), XOR-swizzled:
// k-group g of row r lives in slot s = g ^ (r&7). ds_read_b128 by 16
// consecutive rows then covers each bank-quad exactly twice (2-way = free).
//
// Grid 1D (+z batch), XCD-aware decode (id&7 = xcd owns contiguous bm chunk).
// EPI 0: bf16 C=v*scale | 1: bf16 C=gelu(v) | 2: fp32 C=v+R (C may alias R
// per-element; no restrict, load precedes store).
// CSKIP: skip tiles above diagonal. CKLOOP: Keff=min(K,(bm+1)*128).
// ASPLIT: A rows are split at column Ksp between buffers A/A2 (fused ffn2).
// ---------------------------------------------------------------------------
template <int EPI, bool CSKIP, bool CKLOOP, bool ASPLIT>
__global__ __launch_bounds__(256) void gemm_bt(
    const bf16_t* __restrict__ A, const bf16_t* __restrict__ A2, int lda,
    const bf16_t* __restrict__ B, int ldb,
    void* Cv, int ldc, const float* R,
    int K, int Ksp, int Mt, long long sA, long long sB, long long sC,
    float scale)
{
    int id = blockIdx.x, bz = blockIdx.z;
    int xcd = id & 7, p = id >> 3;
    int chunk = Mt >> 3;
    int bm = xcd * chunk + (p % chunk);
    int bn = p / chunk;
    if (CSKIP && bn > bm) return;

    __shared__ __align__(16) bf16_t At[128 * 64];
    __shared__ __align__(16) bf16_t Bt[128 * 64];
    int t = threadIdx.x;
    int w = t >> 6, l = t & 63;
    int wm = w >> 1, wn = w & 1;
    int lane_m = l & 15, quad = l >> 4;

    const bf16_t* Ag = A + (long long)bz * sA + (size_t)(bm * 128) * lda;
    const bf16_t* Bg = B + (long long)bz * sB + (size_t)(bn * 128) * ldb;

    int Keff = K;
    if (CKLOOP) {
        int kk = (bm + 1) * 128;
        if (kk < K) Keff = kk;
    }

    f32x4 acc[4][4] = {};

    // staging: thread (w,l) handles chunks cl = w*64 + 256*j + l, j=0..3.
    // cl -> LDS row r=cl>>3, slot s=cl&7; source k-group g = s ^ (r&7).
    // r = w*8 + 32*j + (l>>3); s = l&7; r&7 = (l>>3)&7  (w*8,32j = 0 mod 8)
    int rb = w * 8 + (l >> 3);
    int g0 = ((l & 7) ^ ((l >> 3) & 7)) * 8;
    const bf16_t* a0[4];
    const bf16_t* a1[4];
    const bf16_t* b0[4];
#pragma unroll
    for (int j = 0; j < 4; j++) {
        size_t ro = (size_t)(rb + 32 * j);
        a0[j] = Ag + ro * lda + g0;
        if (ASPLIT) a1[j] = A2 + (long long)bz * sA + (size_t)(bm * 128) * lda
                           + ro * lda + g0;
        b0[j] = Bg + ro * ldb + g0;
    }

    // ds_read slots: row = wm*64+mi*16+lane_m -> row&7 = lane_m&7
    int s0 = (quad ^ (lane_m & 7)) * 8;        // k-half 0: g = quad
    int s1 = ((4 + quad) ^ (lane_m & 7)) * 8;  // k-half 1: g = 4+quad

    for (int kt = 0; kt < Keff; kt += 64) {
        __syncthreads();
#pragma unroll
        for (int j = 0; j < 4; j++) {
            const bf16_t* pa = a0[j] + kt;
            if (ASPLIT && kt >= Ksp) pa = a1[j] + (kt - Ksp);
            LDS16(pa, At + (size_t)w * 512 + j * 2048);
            LDS16(b0[j] + kt, Bt + (size_t)w * 512 + j * 2048);
        }
        __syncthreads();

#pragma unroll
        for (int h = 0; h < 2; h++) {
            int sh = h ? s1 : s0;
            bf16x8 af[4], bfr[4];
#pragma unroll
            for (int mi = 0; mi < 4; mi++)
                af[mi] = *(const bf16x8*)(At + (wm * 64 + mi * 16 + lane_m) * 64 + sh);
#pragma unroll
            for (int ni = 0; ni < 4; ni++)
                bfr[ni] = *(const bf16x8*)(Bt + (wn * 64 + ni * 16 + lane_m) * 64 + sh);
#pragma unroll
            for (int mi = 0; mi < 4; mi++)
#pragma unroll
                for (int ni = 0; ni < 4; ni++)
                    acc[mi][ni] = __builtin_amdgcn_mfma_f32_16x16x32_bf16(
                        af[mi], bfr[ni], acc[mi][ni], 0, 0, 0);
        }
    }

    long long cbase = (long long)bz * sC;
#pragma unroll
    for (int mi = 0; mi < 4; mi++) {
#pragma unroll
        for (int r = 0; r < 4; r++) {
            int row = bm * 128 + wm * 64 + mi * 16 + quad * 4 + r;
#pragma unroll
            for (int ni = 0; ni < 4; ni++) {
                int col = bn * 128 + wn * 64 + ni * 16 + lane_m;
                float v = acc[mi][ni][r];
                size_t idx = (size_t)(cbase + (long long)row * ldc + col);
                if (EPI == 0) {
                    ((bf16_t*)Cv)[idx] = (bf16_t)(v * scale);
                } else if (EPI == 1) {
                    float g = 0.5f * v * (1.0f + erff(v * 0.70710678118654752f));
                    ((bf16_t*)Cv)[idx] = (bf16_t)g;
                } else {
                    float rv = R[(size_t)row * ldc + col];
                    ((float*)Cv)[idx] = v + rv;
                }
            }
        }
    }
}

// ---------------------------------------------------------------------------
// Launch. fp32 I/O, bf16 internals.
// ws layout (MiB): [0,6) qkvb | [6,8) opT | [8,16) f1b | [16,24) f2b
//   [24,40) h1 -> VT -> h2 (disjoint lifetimes)
//   [40,88) QKVb; then AV [40,56); then G0 [40,72)
//   [72,104) G1  (only if ws_size >= 104 MiB -> fused single ffn2)
// SP (bf16 32 MiB) lives in d_out (fp32, unused until out_proj).
// ---------------------------------------------------------------------------
extern "C" void kernel_launch(void* const* d_in, const int* in_sizes, int n_in,
                              void* d_out, int out_size, void* d_ws, size_t ws_size,
                              hipStream_t stream)
{
    (void)in_sizes; (void)n_in; (void)out_size;
    const float* x    = (const float*)d_in[0];
    const float* ln1  = (const float*)d_in[1];
    const float* ln2  = (const float*)d_in[2];
    const float* ffn1 = (const float*)d_in[3];
    const float* ffn2 = (const float*)d_in[4];
    const float* kp   = (const float*)d_in[5];
    const float* qp   = (const float*)d_in[6];
    const float* vp   = (const float*)d_in[7];
    const float* op   = (const float*)d_in[8];
    float* out = (float*)d_out;

    const size_t MiB = 1048576;
    char* ws = (char*)d_ws;
    bf16_t* qkvb = (bf16_t*)(ws + 0 * MiB);
    bf16_t* opT  = (bf16_t*)(ws + 6 * MiB);
    bf16_t* f1b  = (bf16_t*)(ws + 8 * MiB);
    bf16_t* f2b  = (bf16_t*)(ws + 16 * MiB);
    bf16_t* h1   = (bf16_t*)(ws + 24 * MiB);
    bf16_t* VT   = (bf16_t*)(ws + 24 * MiB);  // h1 dead after QKV gemm
    bf16_t* h2   = (bf16_t*)(ws + 24 * MiB);  // VT dead after AV gemm
    bf16_t* QKVb = (bf16_t*)(ws + 40 * MiB);  // [8192][3072]
    bf16_t* AV   = (bf16_t*)(ws + 40 * MiB);  // QKVb dead after V^T
    bf16_t* G0   = (bf16_t*)(ws + 40 * MiB);  // AV dead after out_proj
    bf16_t* G1   = (bf16_t*)(ws + 72 * MiB);  // big-ws path only
    bf16_t* SP   = (bf16_t*)d_out;
    bool bigws = ws_size >= 104 * MiB;

    dim3 blk(256);
    const int HUGE_K = 1 << 30;

    // 1) prep: weight cvt + out_proj^T + rmsnorm1
    prep_kernel<<<dim3(20480), blk, 0, stream>>>(
        qp, kp, vp, ffn1, ffn2, op, x, ln1, qkvb, f1b, f2b, opT, h1);

    // 2) fused QKV: [8192,1024] x [3072,1024]^T -> QKVb
    gemm_bt<0, false, false, false><<<dim3(1536), blk, 0, stream>>>(
        h1, h1, 1024, qkvb, 1024, QKVb, 3072, nullptr,
        1024, HUGE_K, 64, 0, 0, 0, 1.0f);

    // 3) scores = Q K^T / 32, lower-triangular tiles -> SP (in d_out)
    gemm_bt<0, true, false, false><<<dim3(256, 1, 4), blk, 0, stream>>>(
        QKVb, QKVb, 3072, QKVb + 1024, 3072, SP, 2048, nullptr,
        1024, HUGE_K, 16,
        (long long)2048 * 3072, (long long)2048 * 3072, (long long)2048 * 2048,
        1.0f / 32.0f);

    // 4) V -> V^T per batch (V = QKVb cols [2048,3072); VT into h1 slot)
    transpose_bf16<<<dim3(32, 64, 4), blk, 0, stream>>>(
        QKVb + 2048, VT, 2048, 3072,
        (long long)2048 * 3072, (long long)1024 * 2048);

    // 5) causal softmax in place (vectorized, causal-skip)
    causal_softmax_kernel<<<dim3(2048, 4), blk, 0, stream>>>(SP);

    // 6) AV = P @ V (B = V^T [1024][2048], causal K clamp)
    gemm_bt<0, false, true, false><<<dim3(128, 1, 4), blk, 0, stream>>>(
        SP, SP, 2048, VT, 2048, AV, 1024, nullptr,
        2048, HUGE_K, 16,
        (long long)2048 * 2048, (long long)1024 * 2048, (long long)2048 * 1024,
        1.0f);

    // 7) out = x + AV @ out_proj^T  (fp32 into d_out; SP dead)
    gemm_bt<2, false, false, false><<<dim3(512), blk, 0, stream>>>(
        AV, AV, 1024, opT, 1024, out, 1024, x,
        1024, HUGE_K, 64, 0, 0, 0, 1.0f);

    // 8) h2 = rmsnorm(x) * ln2
    rmsnorm_kernel<<<dim3(8192), blk, 0, stream>>>(x, ln2, h2);

    if (bigws) {
        // 9) G0/G1 = gelu(h2 @ ffn1_half^T)
        gemm_bt<1, false, false, false><<<dim3(1024), blk, 0, stream>>>(
            h2, h2, 1024, f1b, 1024, G0, 2048, nullptr,
            1024, HUGE_K, 64, 0, 0, 0, 1.0f);
        gemm_bt<1, false, false, false><<<dim3(1024), blk, 0, stream>>>(
            h2, h2, 1024, f1b + (size_t)2048 * 1024, 1024, G1, 2048, nullptr,
            1024, HUGE_K, 64, 0, 0, 0, 1.0f);
        // 10) out += G @ ffn2^T, single K=4096 pass over split G
        gemm_bt<2, false, false, true><<<dim3(512), blk, 0, stream>>>(
            G0, G1, 2048, f2b, 4096, out, 1024, out,
            4096, 2048, 64, 0, 0, 0, 1.0f);
    } else {
        for (int half = 0; half < 2; half++) {
            gemm_bt<1, false, false, false><<<dim3(1024), blk, 0, stream>>>(
                h2, h2, 1024, f1b + (size_t)half * 2048 * 1024, 1024, G0, 2048,
                nullptr, 1024, HUGE_K, 64, 0, 0, 0, 1.0f);
            gemm_bt<2, false, false, false><<<dim3(512), blk, 0, stream>>>(
                G0, G0, 2048, f2b + half * 2048, 4096, out, 1024, out,
                2048, HUGE_K, 64, 0, 0, 0, 1.0f);
        }
    }
}